// Round 5
// baseline (247.013 us; speedup 1.0000x reference)
//
#include <hip/hip_runtime.h>

#define B_ 2
#define S_ 8192
#define H_ 8
#define D_ 64
#define HD_ 512
#define WIN_ 512

typedef __bf16 bf16x8 __attribute__((ext_vector_type(8)));
typedef float f32x4 __attribute__((ext_vector_type(4)));
typedef unsigned short u16;
typedef unsigned int u32;

__device__ __forceinline__ u16 f2bf(float f) {
  u32 u = __float_as_uint(f);
  u += 0x7FFFu + ((u >> 16) & 1u);
  return (u16)(u >> 16);
}

__device__ __forceinline__ bf16x8 cvt8s(const float* p, float s) {
  const float4 a = *(const float4*)p;
  const float4 b = *(const float4*)(p + 4);
  union { u16 s[8]; bf16x8 v; } r;
  r.s[0] = f2bf(a.x * s); r.s[1] = f2bf(a.y * s); r.s[2] = f2bf(a.z * s); r.s[3] = f2bf(a.w * s);
  r.s[4] = f2bf(b.x * s); r.s[5] = f2bf(b.y * s); r.s[6] = f2bf(b.z * s); r.s[7] = f2bf(b.w * s);
  return r.v;
}

#define MFMA(a, b, c) __builtin_amdgcn_mfma_f32_16x16x32_bf16(a, b, c, 0, 0, 0)

// ---------------------------------------------------------------------------
// V [B,S,H,D] fp32 -> Vt [B,H,D,S] bf16  (LDS-tiled transpose, 64x64 tiles)
// ---------------------------------------------------------------------------
__global__ __launch_bounds__(256) void vtrans_kernel(const float* __restrict__ v,
                                                     u16* __restrict__ vt) {
  const int t = threadIdx.x;
  const int s0 = (blockIdx.x & (S_ / 64 - 1)) * 64;
  const int bh = blockIdx.x >> 7;  // S_/64 = 128
  const int b = bh >> 3, h = bh & 7;
  __shared__ float tile[64][65];
#pragma unroll
  for (int it = 0; it < 16; ++it) {
    int idx = it * 256 + t;
    int r = idx >> 6, c = idx & 63;  // r: s-offset, c: d
    tile[r][c] = v[((size_t)(b * S_ + s0 + r) * H_ + h) * D_ + c];
  }
  __syncthreads();
#pragma unroll
  for (int it = 0; it < 16; ++it) {
    int idx = it * 256 + t;
    int dd = idx >> 6, c = idx & 63;  // dd: d, c: s-offset
    vt[((size_t)(b * H_ + h) * D_ + dd) * S_ + s0 + c] = f2bf(tile[c][dd]);
  }
}

// ---------------------------------------------------------------------------
// generic fp32 -> bf16 conversion (vectorized x4)
// ---------------------------------------------------------------------------
__global__ __launch_bounds__(256) void cvt_kernel(const float* __restrict__ in,
                                                  u16* __restrict__ out, int n4) {
  int i = blockIdx.x * 256 + threadIdx.x;
  if (i < n4) {
    float4 f = ((const float4*)in)[i];
    ushort4 r;
    r.x = f2bf(f.x); r.y = f2bf(f.y); r.z = f2bf(f.z); r.w = f2bf(f.w);
    ((ushort4*)out)[i] = r;
  }
}

// ---------------------------------------------------------------------------
// Sliding-window flash attention, fixed-reference exp (no online softmax).
// Q pre-scaled by 0.125*log2(e) so p = exp2(mfma_out) directly.
// One wave per 16-query tile; masks only on first (window) / last (causal)
// key tile — interior tiles are provably fully valid.
// ---------------------------------------------------------------------------
template <bool MASKED>
__device__ __forceinline__ void tile_step(int kt, int q0, int b, int h, int lg, int lj,
                                          const u16* __restrict__ kb,
                                          const u16* __restrict__ vt,
                                          bf16x8 aq0, bf16x8 aq1,
                                          f32x4& o0, f32x4& o1, f32x4& o2, f32x4& o3,
                                          float* lacc, u16* plds_wave) {
  u16* pslot = plds_wave + ((kt >> 5) & 1) * 512;  // double-buffer by tile parity
  const u16* kb0 = kb + ((size_t)(b * S_ + kt + lj) * H_ + h) * D_;
  const u16* kb1 = kb0 + (size_t)16 * H_ * D_;
  bf16x8 k00 = *(const bf16x8*)(kb0 + lg * 8);
  bf16x8 k01 = *(const bf16x8*)(kb0 + 32 + lg * 8);
  bf16x8 k10 = *(const bf16x8*)(kb1 + lg * 8);
  bf16x8 k11 = *(const bf16x8*)(kb1 + 32 + lg * 8);

  f32x4 sA = {0.f, 0.f, 0.f, 0.f}, sB = sA;
  sA = MFMA(aq0, k00, sA);
  sA = MFMA(aq1, k01, sA);
  sB = MFMA(aq0, k10, sB);
  sB = MFMA(aq1, k11, sB);

  float pa[4], pb[4];
#pragma unroll
  for (int r = 0; r < 4; ++r) {
    if (MASKED) {
      const int qpos = q0 + lg * 4 + r;
      const int kA = kt + lj, kB = kA + 16;
      const bool okA = (kA <= qpos) && (kA > qpos - WIN_);
      const bool okB = (kB <= qpos) && (kB > qpos - WIN_);
      pa[r] = okA ? __builtin_amdgcn_exp2f(sA[r]) : 0.f;
      pb[r] = okB ? __builtin_amdgcn_exp2f(sB[r]) : 0.f;
    } else {
      pa[r] = __builtin_amdgcn_exp2f(sA[r]);
      pb[r] = __builtin_amdgcn_exp2f(sB[r]);
    }
    lacc[r] += pa[r] + pb[r];
  }

  // P (D-layout) -> A-layout via per-wave LDS roundtrip (intra-wave, no barrier)
#pragma unroll
  for (int r = 0; r < 4; ++r) {
    pslot[(lg * 4 + r) * 32 + lj] = f2bf(pa[r]);
    pslot[(lg * 4 + r) * 32 + 16 + lj] = f2bf(pb[r]);
  }
  bf16x8 ap = *(const bf16x8*)(pslot + lj * 32 + lg * 8);

  const u16* vbase = vt + ((size_t)(b * H_ + h) * D_ + lj) * S_ + kt + lg * 8;
  o0 = MFMA(ap, *(const bf16x8*)(vbase + (size_t)0 * 16 * S_), o0);
  o1 = MFMA(ap, *(const bf16x8*)(vbase + (size_t)1 * 16 * S_), o1);
  o2 = MFMA(ap, *(const bf16x8*)(vbase + (size_t)2 * 16 * S_), o2);
  o3 = MFMA(ap, *(const bf16x8*)(vbase + (size_t)3 * 16 * S_), o3);
}

__global__ __launch_bounds__(256) void attn_kernel(const float* __restrict__ q,
                                                   const u16* __restrict__ kb,
                                                   const u16* __restrict__ vt,
                                                   u16* __restrict__ attn) {
  const int lane = threadIdx.x & 63;
  const int wave = threadIdx.x >> 6;
  const int lg = lane >> 4;      // 0..3
  const int lj = lane & 15;      // 0..15
  // XCD-aware swizzle: 2048 blocks, 8 XCDs, 256-block contiguous chunks
  const int bid = (int)blockIdx.x;
  const int swz = (bid & 7) * 256 + (bid >> 3);
  const int qc = swz & 127;
  const int bh = swz >> 7;
  const int b = bh >> 3, h = bh & 7;
  const int q0 = qc * 64 + wave * 16;

  __shared__ __align__(16) u16 plds[4][2][16][32];
  u16* plds_wave = &plds[wave][0][0][0];

  // Q fragments pre-scaled by 1/sqrt(D) * log2(e): exp2(mfma) == softmax exp
  const float qscale = 0.125f * 1.4426950408889634f;
  bf16x8 aq0, aq1;
  {
    const float* qrow = q + ((size_t)(b * S_ + q0 + lj) * H_ + h) * D_;
    aq0 = cvt8s(qrow + lg * 8, qscale);
    aq1 = cvt8s(qrow + 32 + lg * 8, qscale);
  }

  f32x4 o0 = {0.f, 0.f, 0.f, 0.f}, o1 = o0, o2 = o0, o3 = o0;
  float lacc[4] = {0.f, 0.f, 0.f, 0.f};

  int kstart = q0 - (WIN_ - 1);
  if (kstart < 0) kstart = 0;
  kstart &= ~31;
  const int ktlast = (q0 + 15) & ~31;

  int kt = kstart;
  if (q0 >= WIN_ && kt < ktlast) {  // window-edge tile (never also the last tile here)
    tile_step<true>(kt, q0, b, h, lg, lj, kb, vt, aq0, aq1, o0, o1, o2, o3, lacc, plds_wave);
    kt += 32;
  }
  for (; kt < ktlast; kt += 32) {   // interior: fully valid, maskless
    tile_step<false>(kt, q0, b, h, lg, lj, kb, vt, aq0, aq1, o0, o1, o2, o3, lacc, plds_wave);
  }
  // causal-edge tile (also covers the single-tile case with both masks)
  tile_step<true>(ktlast, q0, b, h, lg, lj, kb, vt, aq0, aq1, o0, o1, o2, o3, lacc, plds_wave);

  // ---- epilogue: reduce l across the 16 key-columns, normalize, store ----
#pragma unroll
  for (int r = 0; r < 4; ++r) {
    float l = lacc[r];
    l += __shfl_xor(l, 1);
    l += __shfl_xor(l, 2);
    l += __shfl_xor(l, 4);
    l += __shfl_xor(l, 8);
    const float inv = 1.0f / l;
    const int row = q0 + lg * 4 + r;
    u16* orow = attn + (size_t)(b * S_ + row) * HD_ + h * D_;
    orow[0 * 16 + lj] = f2bf(o0[r] * inv);
    orow[1 * 16 + lj] = f2bf(o1[r] * inv);
    orow[2 * 16 + lj] = f2bf(o2[r] * inv);
    orow[3 * 16 + lj] = f2bf(o3[r] * inv);
  }
}

// ---------------------------------------------------------------------------
// out = attn[16384,512](bf16) @ W^T (W bf16 row-major as B[k][o]=W[o][k]) + bias
// ---------------------------------------------------------------------------
__global__ __launch_bounds__(256) void gemm_kernel(const u16* __restrict__ A,
                                                   const u16* __restrict__ Wb,
                                                   const float* __restrict__ bias,
                                                   float* __restrict__ out) {
  const int lane = threadIdx.x & 63;
  const int wave = threadIdx.x >> 6;
  const int lg = lane >> 4, lj = lane & 15;
  const int rb = blockIdx.x >> 3;  // 256 row blocks
  const int cb = blockIdx.x & 7;   // 8 col blocks
  const int n0 = rb * 64 + (wave >> 1) * 32;
  const int o0 = cb * 64 + (wave & 1) * 32;

  f32x4 c00 = {0.f, 0.f, 0.f, 0.f}, c01 = c00, c10 = c00, c11 = c00;

  for (int kt = 0; kt < HD_; kt += 32) {
    bf16x8 a0 = *(const bf16x8*)(A + (size_t)(n0 + lj) * HD_ + kt + lg * 8);
    bf16x8 a1 = *(const bf16x8*)(A + (size_t)(n0 + 16 + lj) * HD_ + kt + lg * 8);
    bf16x8 b0 = *(const bf16x8*)(Wb + (size_t)(o0 + lj) * HD_ + kt + lg * 8);
    bf16x8 b1 = *(const bf16x8*)(Wb + (size_t)(o0 + 16 + lj) * HD_ + kt + lg * 8);
    c00 = MFMA(a0, b0, c00);
    c01 = MFMA(a0, b1, c01);
    c10 = MFMA(a1, b0, c10);
    c11 = MFMA(a1, b1, c11);
  }

#pragma unroll
  for (int r = 0; r < 4; ++r) {
    const int r0 = n0 + lg * 4 + r;
    const int r1 = r0 + 16;
    out[(size_t)r0 * HD_ + o0 + lj] = c00[r] + bias[o0 + lj];
    out[(size_t)r0 * HD_ + o0 + 16 + lj] = c01[r] + bias[o0 + 16 + lj];
    out[(size_t)r1 * HD_ + o0 + lj] = c10[r] + bias[o0 + lj];
    out[(size_t)r1 * HD_ + o0 + 16 + lj] = c11[r] + bias[o0 + 16 + lj];
  }
}

// ---------------------------------------------------------------------------
extern "C" void kernel_launch(void* const* d_in, const int* in_sizes, int n_in,
                              void* d_out, int out_size, void* d_ws, size_t ws_size,
                              hipStream_t stream) {
  const float* q = (const float*)d_in[0];
  const float* k = (const float*)d_in[1];
  const float* v = (const float*)d_in[2];
  const float* w = (const float*)d_in[3];
  const float* bias = (const float*)d_in[4];
  float* out = (float*)d_out;

  char* ws = (char*)d_ws;
  u16* vt = (u16*)ws;                        // 16,777,216 B : V^T bf16 [B,H,D,S]
  u16* kbb = (u16*)(ws + 16777216);          // 16,777,216 B : K bf16 [B,S,H,D]
  u16* attn = (u16*)(ws + 33554432);         // 16,777,216 B : attn bf16 [B*S, 512]
  u16* wb = (u16*)(ws + 50331648);           //    524,288 B : W bf16 [512,512]

  hipLaunchKernelGGL(vtrans_kernel, dim3(2048), dim3(256), 0, stream, v, vt);
  hipLaunchKernelGGL(cvt_kernel, dim3(8192), dim3(256), 0, stream, k, kbb, 2097152);
  hipLaunchKernelGGL(cvt_kernel, dim3(256), dim3(256), 0, stream, w, wb, 65536);
  hipLaunchKernelGGL(attn_kernel, dim3(2048), dim3(256), 0, stream, q, kbb, vt, attn);
  hipLaunchKernelGGL(gemm_kernel, dim3(2048), dim3(256), 0, stream, attn, wb, bias, out);
}

// Round 6
// 189.295 us; speedup vs baseline: 1.3049x; 1.3049x over previous
//
#include <hip/hip_runtime.h>

#define B_ 2
#define S_ 8192
#define H_ 8
#define D_ 64
#define HD_ 512
#define WIN_ 512

typedef __bf16 bf16x8 __attribute__((ext_vector_type(8)));
typedef float f32x4 __attribute__((ext_vector_type(4)));
typedef unsigned short u16;
typedef unsigned int u32;

__device__ __forceinline__ u16 f2bf(float f) {
  u32 u = __float_as_uint(f);
  u += 0x7FFFu + ((u >> 16) & 1u);
  return (u16)(u >> 16);
}

__device__ __forceinline__ bf16x8 cvt8s(const float* p, float s) {
  const float4 a = *(const float4*)p;
  const float4 b = *(const float4*)(p + 4);
  union { u16 s[8]; bf16x8 v; } r;
  r.s[0] = f2bf(a.x * s); r.s[1] = f2bf(a.y * s); r.s[2] = f2bf(a.z * s); r.s[3] = f2bf(a.w * s);
  r.s[4] = f2bf(b.x * s); r.s[5] = f2bf(b.y * s); r.s[6] = f2bf(b.z * s); r.s[7] = f2bf(b.w * s);
  return r.v;
}

#define MFMA(a, b, c) __builtin_amdgcn_mfma_f32_16x16x32_bf16(a, b, c, 0, 0, 0)

// ---------------------------------------------------------------------------
// V [B,S,H,D] fp32 -> Vt [B,H,D,S] bf16  (LDS-tiled transpose, 64x64 tiles)
// ---------------------------------------------------------------------------
__global__ __launch_bounds__(256) void vtrans_kernel(const float* __restrict__ v,
                                                     u16* __restrict__ vt) {
  const int t = threadIdx.x;
  const int s0 = (blockIdx.x & (S_ / 64 - 1)) * 64;
  const int bh = blockIdx.x >> 7;  // S_/64 = 128
  const int b = bh >> 3, h = bh & 7;
  __shared__ float tile[64][65];
#pragma unroll
  for (int it = 0; it < 16; ++it) {
    int idx = it * 256 + t;
    int r = idx >> 6, c = idx & 63;
    tile[r][c] = v[((size_t)(b * S_ + s0 + r) * H_ + h) * D_ + c];
  }
  __syncthreads();
#pragma unroll
  for (int it = 0; it < 16; ++it) {
    int idx = it * 256 + t;
    int dd = idx >> 6, c = idx & 63;
    vt[((size_t)(b * H_ + h) * D_ + dd) * S_ + s0 + c] = f2bf(tile[c][dd]);
  }
}

// ---------------------------------------------------------------------------
// generic fp32 -> bf16 conversion (vectorized x4)
// ---------------------------------------------------------------------------
__global__ __launch_bounds__(256) void cvt_kernel(const float* __restrict__ in,
                                                  u16* __restrict__ out, int n4) {
  int i = blockIdx.x * 256 + threadIdx.x;
  if (i < n4) {
    float4 f = ((const float4*)in)[i];
    ushort4 r;
    r.x = f2bf(f.x); r.y = f2bf(f.y); r.z = f2bf(f.z); r.w = f2bf(f.w);
    ((ushort4*)out)[i] = r;
  }
}

// ---------------------------------------------------------------------------
// Sliding-window flash attention, fixed-reference exp, 32 queries per wave,
// register-prefetched K (tile t+1 in flight during tile t), V issued at tile
// start so PV's wait leaves the K prefetch outstanding.
// ---------------------------------------------------------------------------
__global__ __launch_bounds__(256) void attn_kernel(const float* __restrict__ q,
                                                   const u16* __restrict__ kb,
                                                   const u16* __restrict__ vt,
                                                   u16* __restrict__ attn) {
  const int lane = threadIdx.x & 63;
  const int wave = threadIdx.x >> 6;
  const int lg = lane >> 4;      // 0..3
  const int lj = lane & 15;      // 0..15
  // XCD swizzle: 1024 blocks, 8 XCDs, 128-block contiguous chunks (bijective)
  const int bid = (int)blockIdx.x;
  const int swz = (bid & 7) * 128 + (bid >> 3);
  const int qc = swz & 63;           // S_/128 = 64 query chunks
  const int bh = swz >> 6;
  const int b = bh >> 3, h = bh & 7;
  const int q0 = qc * 128 + wave * 32;   // 32 queries per wave

  __shared__ __align__(16) u16 plds[4][2][2][16][32];  // [wave][parity][qset]

  const float qscale = 0.125f * 1.4426950408889634f;  // 1/sqrt(D) * log2(e)
  bf16x8 aq00, aq01, aq10, aq11;
  {
    const float* qr0 = q + ((size_t)(b * S_ + q0 + lj) * H_ + h) * D_;
    const float* qr1 = q + ((size_t)(b * S_ + q0 + 16 + lj) * H_ + h) * D_;
    aq00 = cvt8s(qr0 + lg * 8, qscale);
    aq01 = cvt8s(qr0 + 32 + lg * 8, qscale);
    aq10 = cvt8s(qr1 + lg * 8, qscale);
    aq11 = cvt8s(qr1 + 32 + lg * 8, qscale);
  }

  f32x4 o[2][4];
#pragma unroll
  for (int qs = 0; qs < 2; ++qs)
#pragma unroll
    for (int g = 0; g < 4; ++g) o[qs][g] = (f32x4){0.f, 0.f, 0.f, 0.f};
  float lacc[2][4] = {};

  const u16* kbl = kb + (size_t)b * S_ * HD_ + (size_t)lj * HD_ + h * D_ + lg * 8;
  const u16* vbl = vt + ((size_t)(b * H_ + h) * D_ + lj) * S_ + lg * 8;

  int kstart = q0 - (WIN_ - 1);
  if (kstart < 0) kstart = 0;
  kstart &= ~31;
  const int ktlast = q0;  // q0 multiple of 32; last key tile starts at q0

  bf16x8 kc0, kc1, kc2, kc3, kn0, kn1, kn2, kn3;

#define LOADK_(KT, ra, rb, rc, rd)                          \
  { const u16* p_ = kbl + (size_t)(KT) * HD_;               \
    ra = *(const bf16x8*)p_;                                \
    rb = *(const bf16x8*)(p_ + 32);                         \
    rc = *(const bf16x8*)(p_ + 16 * HD_);                   \
    rd = *(const bf16x8*)(p_ + 16 * HD_ + 32); }

  // mode: 0 = maskless interior, 1 = window edge, 2 = causal edge
  auto step = [&](int kt, int mode, bool prefetch) {
    // V for THIS tile first (oldest in vmcnt FIFO), then K for NEXT tile.
    const u16* vp = vbl + kt;
    bf16x8 v0 = *(const bf16x8*)vp;
    bf16x8 v1 = *(const bf16x8*)(vp + (size_t)16 * S_);
    bf16x8 v2 = *(const bf16x8*)(vp + (size_t)32 * S_);
    bf16x8 v3 = *(const bf16x8*)(vp + (size_t)48 * S_);
    if (prefetch) LOADK_(kt + 32, kn0, kn1, kn2, kn3);
    const int par = (kt >> 5) & 1;
#pragma unroll
    for (int qs = 0; qs < 2; ++qs) {
      const bf16x8 a0 = qs ? aq10 : aq00;
      const bf16x8 a1 = qs ? aq11 : aq01;
      f32x4 sA = {0.f, 0.f, 0.f, 0.f}, sB = sA;
      sA = MFMA(a0, kc0, sA);
      sA = MFMA(a1, kc1, sA);
      sB = MFMA(a0, kc2, sB);
      sB = MFMA(a1, kc3, sB);
      float pa[4], pb[4];
#pragma unroll
      for (int r = 0; r < 4; ++r) {
        float ea = __builtin_amdgcn_exp2f(sA[r]);
        float eb = __builtin_amdgcn_exp2f(sB[r]);
        if (mode) {
          const int qpos = q0 + qs * 16 + lg * 4 + r;
          const int kA = kt + lj, kB = kA + 16;
          const bool okA = (mode == 2) ? (kA <= qpos) : (kA > qpos - WIN_);
          const bool okB = (mode == 2) ? (kB <= qpos) : (kB > qpos - WIN_);
          ea = okA ? ea : 0.f;
          eb = okB ? eb : 0.f;
        }
        pa[r] = ea; pb[r] = eb;
        lacc[qs][r] += ea + eb;
      }
      // P (D-layout) -> A-layout via per-wave LDS roundtrip
      u16* ps = &plds[wave][par][qs][0][0];
#pragma unroll
      for (int r = 0; r < 4; ++r) {
        ps[(lg * 4 + r) * 32 + lj] = f2bf(pa[r]);
        ps[(lg * 4 + r) * 32 + 16 + lj] = f2bf(pb[r]);
      }
      bf16x8 ap = *(const bf16x8*)(ps + lj * 32 + lg * 8);
      o[qs][0] = MFMA(ap, v0, o[qs][0]);
      o[qs][1] = MFMA(ap, v1, o[qs][1]);
      o[qs][2] = MFMA(ap, v2, o[qs][2]);
      o[qs][3] = MFMA(ap, v3, o[qs][3]);
    }
    if (prefetch) { kc0 = kn0; kc1 = kn1; kc2 = kn2; kc3 = kn3; }
  };

  int kt = kstart;
  LOADK_(kt, kc0, kc1, kc2, kc3);
  if (q0 >= WIN_) {           // window-masked first tile (never also the last)
    step(kt, 1, true);
    kt += 32;
  }
  for (; kt < ktlast; kt += 32) {  // interior: provably fully valid
    step(kt, 0, true);
  }
  step(ktlast, 2, false);     // causal-masked last tile

  // ---- epilogue: reduce l over 16 key-columns, normalize, store bf16 ----
#pragma unroll
  for (int qs = 0; qs < 2; ++qs) {
#pragma unroll
    for (int r = 0; r < 4; ++r) {
      float l = lacc[qs][r];
      l += __shfl_xor(l, 1);
      l += __shfl_xor(l, 2);
      l += __shfl_xor(l, 4);
      l += __shfl_xor(l, 8);
      const float inv = 1.0f / l;
      const int row = q0 + qs * 16 + lg * 4 + r;
      u16* orow = attn + (size_t)(b * S_ + row) * HD_ + h * D_;
      orow[lj] = f2bf(o[qs][0][r] * inv);
      orow[16 + lj] = f2bf(o[qs][1][r] * inv);
      orow[32 + lj] = f2bf(o[qs][2][r] * inv);
      orow[48 + lj] = f2bf(o[qs][3][r] * inv);
    }
  }
}

// ---------------------------------------------------------------------------
// out = attn[16384,512](bf16) @ W^T (W bf16 row-major as B[k][o]=W[o][k]) + bias
// ---------------------------------------------------------------------------
__global__ __launch_bounds__(256) void gemm_kernel(const u16* __restrict__ A,
                                                   const u16* __restrict__ Wb,
                                                   const float* __restrict__ bias,
                                                   float* __restrict__ out) {
  const int lane = threadIdx.x & 63;
  const int wave = threadIdx.x >> 6;
  const int lg = lane >> 4, lj = lane & 15;
  const int rb = blockIdx.x >> 3;  // 256 row blocks
  const int cb = blockIdx.x & 7;   // 8 col blocks
  const int n0 = rb * 64 + (wave >> 1) * 32;
  const int o0 = cb * 64 + (wave & 1) * 32;

  f32x4 c00 = {0.f, 0.f, 0.f, 0.f}, c01 = c00, c10 = c00, c11 = c00;

  for (int kt = 0; kt < HD_; kt += 32) {
    bf16x8 a0 = *(const bf16x8*)(A + (size_t)(n0 + lj) * HD_ + kt + lg * 8);
    bf16x8 a1 = *(const bf16x8*)(A + (size_t)(n0 + 16 + lj) * HD_ + kt + lg * 8);
    bf16x8 b0 = *(const bf16x8*)(Wb + (size_t)(o0 + lj) * HD_ + kt + lg * 8);
    bf16x8 b1 = *(const bf16x8*)(Wb + (size_t)(o0 + 16 + lj) * HD_ + kt + lg * 8);
    c00 = MFMA(a0, b0, c00);
    c01 = MFMA(a0, b1, c01);
    c10 = MFMA(a1, b0, c10);
    c11 = MFMA(a1, b1, c11);
  }

#pragma unroll
  for (int r = 0; r < 4; ++r) {
    const int r0 = n0 + lg * 4 + r;
    const int r1 = r0 + 16;
    out[(size_t)r0 * HD_ + o0 + lj] = c00[r] + bias[o0 + lj];
    out[(size_t)r0 * HD_ + o0 + 16 + lj] = c01[r] + bias[o0 + 16 + lj];
    out[(size_t)r1 * HD_ + o0 + lj] = c10[r] + bias[o0 + lj];
    out[(size_t)r1 * HD_ + o0 + 16 + lj] = c11[r] + bias[o0 + 16 + lj];
  }
}

// ---------------------------------------------------------------------------
extern "C" void kernel_launch(void* const* d_in, const int* in_sizes, int n_in,
                              void* d_out, int out_size, void* d_ws, size_t ws_size,
                              hipStream_t stream) {
  const float* q = (const float*)d_in[0];
  const float* k = (const float*)d_in[1];
  const float* v = (const float*)d_in[2];
  const float* w = (const float*)d_in[3];
  const float* bias = (const float*)d_in[4];
  float* out = (float*)d_out;

  char* ws = (char*)d_ws;
  u16* vt = (u16*)ws;                        // 16,777,216 B : V^T bf16 [B,H,D,S]
  u16* kbb = (u16*)(ws + 16777216);          // 16,777,216 B : K bf16 [B,S,H,D]
  u16* attn = (u16*)(ws + 33554432);         // 16,777,216 B : attn bf16 [B*S, 512]
  u16* wb = (u16*)(ws + 50331648);           //    524,288 B : W bf16 [512,512]

  hipLaunchKernelGGL(vtrans_kernel, dim3(2048), dim3(256), 0, stream, v, vt);
  hipLaunchKernelGGL(cvt_kernel, dim3(8192), dim3(256), 0, stream, k, kbb, 2097152);
  hipLaunchKernelGGL(cvt_kernel, dim3(256), dim3(256), 0, stream, w, wb, 65536);
  // attention: B*H*(S/128) = 1024 blocks x 4 waves (32 queries each)
  hipLaunchKernelGGL(attn_kernel, dim3(1024), dim3(256), 0, stream, q, kbb, vt, attn);
  hipLaunchKernelGGL(gemm_kernel, dim3(2048), dim3(256), 0, stream, attn, wb, bias, out);
}

// Round 7
// 173.779 us; speedup vs baseline: 1.4214x; 1.0893x over previous
//
#include <hip/hip_runtime.h>

#define B_ 2
#define S_ 8192
#define H_ 8
#define D_ 64
#define HD_ 512
#define WIN_ 512

typedef __bf16 bf16x8 __attribute__((ext_vector_type(8)));
typedef float f32x4 __attribute__((ext_vector_type(4)));
typedef unsigned short u16;
typedef unsigned int u32;

__device__ __forceinline__ u16 f2bf(float f) {
  u32 u = __float_as_uint(f);
  u += 0x7FFFu + ((u >> 16) & 1u);
  return (u16)(u >> 16);
}

__device__ __forceinline__ bf16x8 cvt8s(const float* p, float s) {
  const float4 a = *(const float4*)p;
  const float4 b = *(const float4*)(p + 4);
  union { u16 s[8]; bf16x8 v; } r;
  r.s[0] = f2bf(a.x * s); r.s[1] = f2bf(a.y * s); r.s[2] = f2bf(a.z * s); r.s[3] = f2bf(a.w * s);
  r.s[4] = f2bf(b.x * s); r.s[5] = f2bf(b.y * s); r.s[6] = f2bf(b.z * s); r.s[7] = f2bf(b.w * s);
  return r.v;
}

#define MFMA(a, b, c) __builtin_amdgcn_mfma_f32_16x16x32_bf16(a, b, c, 0, 0, 0)

// ---------------------------------------------------------------------------
// V [B,S,H,D] fp32 -> Vt [B,H,D,S] bf16  (LDS-tiled transpose, 64x64 tiles)
// ---------------------------------------------------------------------------
__global__ __launch_bounds__(256) void vtrans_kernel(const float* __restrict__ v,
                                                     u16* __restrict__ vt) {
  const int t = threadIdx.x;
  const int s0 = (blockIdx.x & (S_ / 64 - 1)) * 64;
  const int bh = blockIdx.x >> 7;  // S_/64 = 128
  const int b = bh >> 3, h = bh & 7;
  __shared__ float tile[64][65];
#pragma unroll
  for (int it = 0; it < 16; ++it) {
    int idx = it * 256 + t;
    int r = idx >> 6, c = idx & 63;
    tile[r][c] = v[((size_t)(b * S_ + s0 + r) * H_ + h) * D_ + c];
  }
  __syncthreads();
#pragma unroll
  for (int it = 0; it < 16; ++it) {
    int idx = it * 256 + t;
    int dd = idx >> 6, c = idx & 63;
    vt[((size_t)(b * H_ + h) * D_ + dd) * S_ + s0 + c] = f2bf(tile[c][dd]);
  }
}

// ---------------------------------------------------------------------------
// generic fp32 -> bf16 conversion (vectorized x4)
// ---------------------------------------------------------------------------
__global__ __launch_bounds__(256) void cvt_kernel(const float* __restrict__ in,
                                                  u16* __restrict__ out, int n4) {
  int i = blockIdx.x * 256 + threadIdx.x;
  if (i < n4) {
    float4 f = ((const float4*)in)[i];
    ushort4 r;
    r.x = f2bf(f.x); r.y = f2bf(f.y); r.z = f2bf(f.z); r.w = f2bf(f.w);
    ((ushort4*)out)[i] = r;
  }
}

// ---------------------------------------------------------------------------
// Sliding-window flash attention, fixed-reference exp (partial softmax sums
// combine by addition). Block = 4 waves: 2 query-halves x 2 KEY-SPLITS.
// Each wave: 32 queries, ~half the key window, register-prefetched K,
// V issued first so PV's wait leaves the K prefetch in flight.
// ks=1 waves write partial (o,l) to LDS; ks=0 waves merge+normalize+store.
// ---------------------------------------------------------------------------
__global__ __launch_bounds__(256) void attn_kernel(const float* __restrict__ q,
                                                   const u16* __restrict__ kb,
                                                   const u16* __restrict__ vt,
                                                   u16* __restrict__ attn) {
  const int lane = threadIdx.x & 63;
  const int wave = threadIdx.x >> 6;
  const int qs2 = wave >> 1;     // which 32-query half of the block's 64
  const int ks = wave & 1;       // key-split index
  const int lg = lane >> 4;      // 0..3
  const int lj = lane & 15;      // 0..15
  // XCD swizzle: 2048 blocks, 8 XCDs, 256-block contiguous chunks (bijective)
  const int bid = (int)blockIdx.x;
  const int swz = (bid & 7) * 256 + (bid >> 3);
  const int qc = swz & 127;      // S_/64 = 128 query chunks of 64
  const int bh = swz >> 7;
  const int b = bh >> 3, h = bh & 7;
  const int q0 = qc * 64 + qs2 * 32;

  __shared__ __align__(16) u16 plds[4][2][16][32];  // [wave][qs] P-transpose, 8KB
  __shared__ float redbuf[2][40][64];               // [qs2][j][lane] partials, 20.5KB

  const float qscale = 0.125f * 1.4426950408889634f;  // 1/sqrt(D) * log2(e)
  bf16x8 aq00, aq01, aq10, aq11;
  {
    const float* qr0 = q + ((size_t)(b * S_ + q0 + lj) * H_ + h) * D_;
    const float* qr1 = q + ((size_t)(b * S_ + q0 + 16 + lj) * H_ + h) * D_;
    aq00 = cvt8s(qr0 + lg * 8, qscale);
    aq01 = cvt8s(qr0 + 32 + lg * 8, qscale);
    aq10 = cvt8s(qr1 + lg * 8, qscale);
    aq11 = cvt8s(qr1 + 32 + lg * 8, qscale);
  }

  f32x4 o[2][4];
#pragma unroll
  for (int qs = 0; qs < 2; ++qs)
#pragma unroll
    for (int g = 0; g < 4; ++g) o[qs][g] = (f32x4){0.f, 0.f, 0.f, 0.f};
  float lacc[2][4] = {};

  const u16* kbl = kb + (size_t)b * S_ * HD_ + (size_t)lj * HD_ + h * D_ + lg * 8;
  const u16* vbl = vt + ((size_t)(b * H_ + h) * D_ + lj) * S_ + lg * 8;

  int kstart = q0 - (WIN_ - 1);
  if (kstart < 0) kstart = 0;
  kstart &= ~31;
  const int ntiles = ((q0 - kstart) >> 5) + 1;
  const int nt0 = (ntiles + 1) >> 1;
  const int tb = ks ? nt0 : 0;
  const int te = ks ? ntiles : nt0;

  bf16x8 kc0, kc1, kc2, kc3, kn0, kn1, kn2, kn3;

#define LOADK_(KT, ra, rb, rc, rd)                          \
  { const u16* p_ = kbl + (size_t)(KT) * HD_;               \
    ra = *(const bf16x8*)p_;                                \
    rb = *(const bf16x8*)(p_ + 32);                         \
    rc = *(const bf16x8*)(p_ + 16 * HD_);                   \
    rd = *(const bf16x8*)(p_ + 16 * HD_ + 32); }

  // mode: 0 = maskless interior, 1 = window edge, 2 = causal edge
  auto step = [&](int kt, int mode, bool prefetch) {
    const u16* vp = vbl + kt;
    bf16x8 v0 = *(const bf16x8*)vp;
    bf16x8 v1 = *(const bf16x8*)(vp + (size_t)16 * S_);
    bf16x8 v2 = *(const bf16x8*)(vp + (size_t)32 * S_);
    bf16x8 v3 = *(const bf16x8*)(vp + (size_t)48 * S_);
    if (prefetch) LOADK_(kt + 32, kn0, kn1, kn2, kn3);
#pragma unroll
    for (int qs = 0; qs < 2; ++qs) {
      const bf16x8 a0 = qs ? aq10 : aq00;
      const bf16x8 a1 = qs ? aq11 : aq01;
      f32x4 sA = {0.f, 0.f, 0.f, 0.f}, sB = sA;
      sA = MFMA(a0, kc0, sA);
      sA = MFMA(a1, kc1, sA);
      sB = MFMA(a0, kc2, sB);
      sB = MFMA(a1, kc3, sB);
      float pa[4], pb[4];
#pragma unroll
      for (int r = 0; r < 4; ++r) {
        float ea = __builtin_amdgcn_exp2f(sA[r]);
        float eb = __builtin_amdgcn_exp2f(sB[r]);
        if (mode) {
          const int qpos = q0 + qs * 16 + lg * 4 + r;
          const int kA = kt + lj, kB = kA + 16;
          const bool okA = (mode == 2) ? (kA <= qpos) : (kA > qpos - WIN_);
          const bool okB = (mode == 2) ? (kB <= qpos) : (kB > qpos - WIN_);
          ea = okA ? ea : 0.f;
          eb = okB ? eb : 0.f;
        }
        pa[r] = ea; pb[r] = eb;
        lacc[qs][r] += ea + eb;
      }
      u16* ps = &plds[wave][qs][0][0];
#pragma unroll
      for (int r = 0; r < 4; ++r) {
        ps[(lg * 4 + r) * 32 + lj] = f2bf(pa[r]);
        ps[(lg * 4 + r) * 32 + 16 + lj] = f2bf(pb[r]);
      }
      bf16x8 ap = *(const bf16x8*)(ps + lj * 32 + lg * 8);
      o[qs][0] = MFMA(ap, v0, o[qs][0]);
      o[qs][1] = MFMA(ap, v1, o[qs][1]);
      o[qs][2] = MFMA(ap, v2, o[qs][2]);
      o[qs][3] = MFMA(ap, v3, o[qs][3]);
    }
    if (prefetch) { kc0 = kn0; kc1 = kn1; kc2 = kn2; kc3 = kn3; }
  };

  if (tb < te) {
    int kt = kstart + tb * 32;
    LOADK_(kt, kc0, kc1, kc2, kc3);
    for (int t = tb; t < te; ++t, kt += 32) {
      const int mode = (t == ntiles - 1) ? 2 : ((t == 0 && q0 >= WIN_) ? 1 : 0);
      step(kt, mode, t + 1 < te);
    }
  }

  // ---- cross-wave partial reduction (key-split) ----
  if (ks == 1) {
#pragma unroll
    for (int qs = 0; qs < 2; ++qs) {
#pragma unroll
      for (int g = 0; g < 4; ++g)
#pragma unroll
        for (int r = 0; r < 4; ++r)
          redbuf[qs2][qs * 16 + g * 4 + r][lane] = o[qs][g][r];
#pragma unroll
      for (int r = 0; r < 4; ++r)
        redbuf[qs2][32 + qs * 4 + r][lane] = lacc[qs][r];
    }
  }
  __syncthreads();
  if (ks == 1) return;

#pragma unroll
  for (int qs = 0; qs < 2; ++qs) {
#pragma unroll
    for (int g = 0; g < 4; ++g)
#pragma unroll
      for (int r = 0; r < 4; ++r)
        o[qs][g][r] += redbuf[qs2][qs * 16 + g * 4 + r][lane];
#pragma unroll
    for (int r = 0; r < 4; ++r)
      lacc[qs][r] += redbuf[qs2][32 + qs * 4 + r][lane];
  }

  // ---- epilogue: reduce l over 16 key-columns, normalize, store bf16 ----
#pragma unroll
  for (int qs = 0; qs < 2; ++qs) {
#pragma unroll
    for (int r = 0; r < 4; ++r) {
      float l = lacc[qs][r];
      l += __shfl_xor(l, 1);
      l += __shfl_xor(l, 2);
      l += __shfl_xor(l, 4);
      l += __shfl_xor(l, 8);
      const float inv = 1.0f / l;
      const int row = q0 + qs * 16 + lg * 4 + r;
      u16* orow = attn + (size_t)(b * S_ + row) * HD_ + h * D_;
      orow[lj] = f2bf(o[qs][0][r] * inv);
      orow[16 + lj] = f2bf(o[qs][1][r] * inv);
      orow[32 + lj] = f2bf(o[qs][2][r] * inv);
      orow[48 + lj] = f2bf(o[qs][3][r] * inv);
    }
  }
}

// ---------------------------------------------------------------------------
// out = attn[16384,512](bf16) @ W^T (W bf16 row-major as B[k][o]=W[o][k]) + bias
// ---------------------------------------------------------------------------
__global__ __launch_bounds__(256) void gemm_kernel(const u16* __restrict__ A,
                                                   const u16* __restrict__ Wb,
                                                   const float* __restrict__ bias,
                                                   float* __restrict__ out) {
  const int lane = threadIdx.x & 63;
  const int wave = threadIdx.x >> 6;
  const int lg = lane >> 4, lj = lane & 15;
  const int rb = blockIdx.x >> 3;  // 256 row blocks
  const int cb = blockIdx.x & 7;   // 8 col blocks
  const int n0 = rb * 64 + (wave >> 1) * 32;
  const int o0 = cb * 64 + (wave & 1) * 32;

  f32x4 c00 = {0.f, 0.f, 0.f, 0.f}, c01 = c00, c10 = c00, c11 = c00;

  for (int kt = 0; kt < HD_; kt += 32) {
    bf16x8 a0 = *(const bf16x8*)(A + (size_t)(n0 + lj) * HD_ + kt + lg * 8);
    bf16x8 a1 = *(const bf16x8*)(A + (size_t)(n0 + 16 + lj) * HD_ + kt + lg * 8);
    bf16x8 b0 = *(const bf16x8*)(Wb + (size_t)(o0 + lj) * HD_ + kt + lg * 8);
    bf16x8 b1 = *(const bf16x8*)(Wb + (size_t)(o0 + 16 + lj) * HD_ + kt + lg * 8);
    c00 = MFMA(a0, b0, c00);
    c01 = MFMA(a0, b1, c01);
    c10 = MFMA(a1, b0, c10);
    c11 = MFMA(a1, b1, c11);
  }

#pragma unroll
  for (int r = 0; r < 4; ++r) {
    const int r0 = n0 + lg * 4 + r;
    const int r1 = r0 + 16;
    out[(size_t)r0 * HD_ + o0 + lj] = c00[r] + bias[o0 + lj];
    out[(size_t)r0 * HD_ + o0 + 16 + lj] = c01[r] + bias[o0 + 16 + lj];
    out[(size_t)r1 * HD_ + o0 + lj] = c10[r] + bias[o0 + lj];
    out[(size_t)r1 * HD_ + o0 + 16 + lj] = c11[r] + bias[o0 + 16 + lj];
  }
}

// ---------------------------------------------------------------------------
extern "C" void kernel_launch(void* const* d_in, const int* in_sizes, int n_in,
                              void* d_out, int out_size, void* d_ws, size_t ws_size,
                              hipStream_t stream) {
  const float* q = (const float*)d_in[0];
  const float* k = (const float*)d_in[1];
  const float* v = (const float*)d_in[2];
  const float* w = (const float*)d_in[3];
  const float* bias = (const float*)d_in[4];
  float* out = (float*)d_out;

  char* ws = (char*)d_ws;
  u16* vt = (u16*)ws;                        // 16,777,216 B : V^T bf16 [B,H,D,S]
  u16* kbb = (u16*)(ws + 16777216);          // 16,777,216 B : K bf16 [B,S,H,D]
  u16* attn = (u16*)(ws + 33554432);         // 16,777,216 B : attn bf16 [B*S, 512]
  u16* wb = (u16*)(ws + 50331648);           //    524,288 B : W bf16 [512,512]

  hipLaunchKernelGGL(vtrans_kernel, dim3(2048), dim3(256), 0, stream, v, vt);
  hipLaunchKernelGGL(cvt_kernel, dim3(8192), dim3(256), 0, stream, k, kbb, 2097152);
  hipLaunchKernelGGL(cvt_kernel, dim3(256), dim3(256), 0, stream, w, wb, 65536);
  // attention: B*H*(S/64) = 2048 blocks x 4 waves (2 q-halves x 2 key-splits)
  hipLaunchKernelGGL(attn_kernel, dim3(2048), dim3(256), 0, stream, q, kbb, vt, attn);
  hipLaunchKernelGGL(gemm_kernel, dim3(2048), dim3(256), 0, stream, attn, wb, bias, out);
}

// Round 8
// 138.883 us; speedup vs baseline: 1.7786x; 1.2513x over previous
//
#include <hip/hip_runtime.h>

#define B_ 2
#define S_ 8192
#define H_ 8
#define D_ 64
#define HD_ 512
#define WIN_ 512

typedef __bf16 bf16x8 __attribute__((ext_vector_type(8)));
typedef float f32x4 __attribute__((ext_vector_type(4)));
typedef unsigned short u16;
typedef unsigned int u32;

__device__ __forceinline__ u16 f2bf(float f) {
  u32 u = __float_as_uint(f);
  u += 0x7FFFu + ((u >> 16) & 1u);
  return (u16)(u >> 16);
}

__device__ __forceinline__ bf16x8 cvt8s(const float* p, float s) {
  const float4 a = *(const float4*)p;
  const float4 b = *(const float4*)(p + 4);
  union { u16 s[8]; bf16x8 v; } r;
  r.s[0] = f2bf(a.x * s); r.s[1] = f2bf(a.y * s); r.s[2] = f2bf(a.z * s); r.s[3] = f2bf(a.w * s);
  r.s[4] = f2bf(b.x * s); r.s[5] = f2bf(b.y * s); r.s[6] = f2bf(b.z * s); r.s[7] = f2bf(b.w * s);
  return r.v;
}

#define MFMA(a, b, c) __builtin_amdgcn_mfma_f32_16x16x32_bf16(a, b, c, 0, 0, 0)

// ---------------------------------------------------------------------------
// V [B,S,H,D] fp32 -> Vt [B,H,D,S] bf16  (LDS-tiled transpose, 64x64 tiles)
// ---------------------------------------------------------------------------
__global__ __launch_bounds__(256) void vtrans_kernel(const float* __restrict__ v,
                                                     u16* __restrict__ vt) {
  const int t = threadIdx.x;
  const int s0 = (blockIdx.x & (S_ / 64 - 1)) * 64;
  const int bh = blockIdx.x >> 7;  // S_/64 = 128
  const int b = bh >> 3, h = bh & 7;
  __shared__ float tile[64][65];
#pragma unroll
  for (int it = 0; it < 16; ++it) {
    int idx = it * 256 + t;
    int r = idx >> 6, c = idx & 63;
    tile[r][c] = v[((size_t)(b * S_ + s0 + r) * H_ + h) * D_ + c];
  }
  __syncthreads();
#pragma unroll
  for (int it = 0; it < 16; ++it) {
    int idx = it * 256 + t;
    int dd = idx >> 6, c = idx & 63;
    vt[((size_t)(b * H_ + h) * D_ + dd) * S_ + s0 + c] = f2bf(tile[c][dd]);
  }
}

// ---------------------------------------------------------------------------
// generic fp32 -> bf16 conversion (vectorized x4)
// ---------------------------------------------------------------------------
__global__ __launch_bounds__(256) void cvt_kernel(const float* __restrict__ in,
                                                  u16* __restrict__ out, int n4) {
  int i = blockIdx.x * 256 + threadIdx.x;
  if (i < n4) {
    float4 f = ((const float4*)in)[i];
    ushort4 r;
    r.x = f2bf(f.x); r.y = f2bf(f.y); r.z = f2bf(f.z); r.w = f2bf(f.w);
    ((ushort4*)out)[i] = r;
  }
}

// ---------------------------------------------------------------------------
// Block-cooperative sliding-window flash attention.
// 512 threads = 8 waves; block owns 128 queries (wave w: 16q at q0blk+16w).
// All waves iterate the block's UNION key-tile range; K (4KB) and V^T (4KB)
// per 32-key tile are staged in LDS once per block (reg-staged, double-
// buffered, one barrier/tile). XOR-swizzled LDS layouts for conflict-light
// ds_read_b128. Fixed-reference exp softmax (no online rescale).
// ---------------------------------------------------------------------------
__global__ __launch_bounds__(512) void attn_kernel(const float* __restrict__ q,
                                                   const u16* __restrict__ kb,
                                                   const u16* __restrict__ vt,
                                                   u16* __restrict__ attn) {
  const int tid = threadIdx.x;
  const int lane = tid & 63;
  const int wave = tid >> 6;
  const int lg = lane >> 4;   // 0..3
  const int lj = lane & 15;   // 0..15
  // XCD swizzle: 1024 blocks, 8 XCDs, 128-block contiguous chunks (bijective)
  const int bid = (int)blockIdx.x;
  const int swz = (bid & 7) * 128 + (bid >> 3);
  const int qc = swz & 63;    // S_/128 = 64 query chunks
  const int bh = swz >> 6;
  const int b = bh >> 3, h = bh & 7;
  const int q0blk = qc * 128;
  const int q0w = q0blk + wave * 16;

  __shared__ __align__(16) u16 klds0[32 * 64], klds1[32 * 64];  // [key][d] swz, 4KB each
  __shared__ __align__(16) u16 vlds0[64 * 32], vlds1[64 * 32];  // [d][key] swz, 4KB each
  __shared__ __align__(16) u16 plds[8][16][32];                 // per-wave P transpose

  // Q fragments pre-scaled by 1/sqrt(D)*log2(e): exp2(mfma) == softmax exp
  const float qscale = 0.125f * 1.4426950408889634f;
  bf16x8 aq0, aq1;
  {
    const float* qrow = q + ((size_t)(b * S_ + q0w + lj) * H_ + h) * D_;
    aq0 = cvt8s(qrow + lg * 8, qscale);
    aq1 = cvt8s(qrow + 32 + lg * 8, qscale);
  }

  f32x4 o0 = {0.f, 0.f, 0.f, 0.f}, o1 = o0, o2 = o0, o3 = o0;
  float lacc[4] = {0.f, 0.f, 0.f, 0.f};

  // tile ranges in absolute key-tile units (key/32)
  const int tbw = (q0w >= WIN_) ? ((q0w - (WIN_ - 1)) >> 5) : 0;
  const int tew = (q0w + 15) >> 5;
  const int tbu = (q0blk >= WIN_) ? ((q0blk - (WIN_ - 1)) >> 5) : 0;
  const int teu = (q0blk + 127) >> 5;
  const bool wmask = (q0w >= WIN_);

  // ---- staging role: waves 0-3 stage K, waves 4-7 stage V^T ----
  const bool isK = (wave < 4);
  const u16* gbase;
  size_t gstep;
  u16 *l0, *l1;
  if (isK) {
    const int chunk = wave * 64 + lane;        // 0..255; 16B each = 4KB K tile
    const int r = chunk >> 3, c = chunk & 7;   // key row r, 16B chunk c
    gbase = kb + ((size_t)(b * S_ + r) * H_ + h) * D_ + c * 8;
    gstep = (size_t)32 * HD_;                  // next key tile
    const int dst = r * 64 + ((c * 8) ^ ((r & 7) << 3));  // elem units, XOR swz
    l0 = klds0 + dst; l1 = klds1 + dst;
  } else {
    const int chunk = (wave - 4) * 64 + lane;  // 0..255; 4KB V^T tile
    const int d = chunk >> 2, c = chunk & 3;   // d row, 16B chunk c
    gbase = vt + ((size_t)(b * H_ + h) * D_ + d) * S_ + c * 8;
    gstep = 32;                                // next 32 keys along S
    const int dst = d * 32 + ((c * 8) ^ ((d & 3) << 3));
    l0 = vlds0 + dst; l1 = vlds1 + dst;
  }

  // ds_read offsets (elem units), same XOR involution as staging
  const int ko0 = lj * 64 + ((lg * 8) ^ ((lj & 7) << 3));         // keys lj,   d 0-31
  const int ko1 = lj * 64 + (((32 + lg * 8)) ^ ((lj & 7) << 3));  // keys lj,   d 32-63
  const int vo = lj * 32 + ((lg * 8) ^ ((lj & 3) << 3));          // d g*16+lj, keys lg*8..

  // ---- prologue: stage tile tbu into buf0; issue load of tile tbu+1 ----
  {
    uint4 g0 = *(const uint4*)(gbase + gstep * tbu);
    *(uint4*)l0 = g0;
  }
  uint4 greg;
  if (tbu < teu) greg = *(const uint4*)(gbase + gstep * (tbu + 1));
  __syncthreads();

  int cur = 0;
  for (int t = tbu; t <= teu; ++t) {
    if (t >= tbw && t <= tew) {   // wave-uniform participation test
      const u16* K = cur ? klds1 : klds0;
      const u16* V = cur ? vlds1 : vlds0;
      bf16x8 k00 = *(const bf16x8*)(K + ko0);
      bf16x8 k01 = *(const bf16x8*)(K + ko1);
      bf16x8 k10 = *(const bf16x8*)(K + ko0 + 1024);
      bf16x8 k11 = *(const bf16x8*)(K + ko1 + 1024);

      f32x4 sA = {0.f, 0.f, 0.f, 0.f}, sB = sA;
      sA = MFMA(aq0, k00, sA);
      sA = MFMA(aq1, k01, sA);
      sB = MFMA(aq0, k10, sB);
      sB = MFMA(aq1, k11, sB);

      const bool edge = (t == tew) || (wmask && t == tbw);
      float pa[4], pb[4];
#pragma unroll
      for (int r = 0; r < 4; ++r) {
        float ea = __builtin_amdgcn_exp2f(sA[r]);
        float eb = __builtin_amdgcn_exp2f(sB[r]);
        if (edge) {
          const int qpos = q0w + lg * 4 + r;
          const int kA = 32 * t + lj, kB = kA + 16;
          const bool okA = (kA <= qpos) && (kA > qpos - WIN_);
          const bool okB = (kB <= qpos) && (kB > qpos - WIN_);
          ea = okA ? ea : 0.f;
          eb = okB ? eb : 0.f;
        }
        pa[r] = ea; pb[r] = eb;
        lacc[r] += ea + eb;
      }

      // P (D-layout) -> A-layout via per-wave LDS roundtrip
      u16* ps = &plds[wave][0][0];
#pragma unroll
      for (int r = 0; r < 4; ++r) {
        ps[(lg * 4 + r) * 32 + lj] = f2bf(pa[r]);
        ps[(lg * 4 + r) * 32 + 16 + lj] = f2bf(pb[r]);
      }
      bf16x8 ap = *(const bf16x8*)(ps + lj * 32 + lg * 8);

      bf16x8 v0 = *(const bf16x8*)(V + vo);
      bf16x8 v1 = *(const bf16x8*)(V + vo + 512);
      bf16x8 v2 = *(const bf16x8*)(V + vo + 1024);
      bf16x8 v3 = *(const bf16x8*)(V + vo + 1536);
      o0 = MFMA(ap, v0, o0);
      o1 = MFMA(ap, v1, o1);
      o2 = MFMA(ap, v2, o2);
      o3 = MFMA(ap, v3, o3);
    }

    // write next tile's staged data (greg) into the other buffer
    if (t < teu) {
      u16* dst = cur ? l0 : l1;
      *(uint4*)dst = greg;
    }
    __syncthreads();   // drains lgkm: staged writes visible; buf[cur] reads done
    if (t + 1 < teu) greg = *(const uint4*)(gbase + gstep * (t + 2));
    cur ^= 1;
  }

  // ---- epilogue: reduce l over 16 key-columns, normalize, store bf16 ----
#pragma unroll
  for (int r = 0; r < 4; ++r) {
    float l = lacc[r];
    l += __shfl_xor(l, 1);
    l += __shfl_xor(l, 2);
    l += __shfl_xor(l, 4);
    l += __shfl_xor(l, 8);
    const float inv = 1.0f / l;
    const int row = q0w + lg * 4 + r;
    u16* orow = attn + (size_t)(b * S_ + row) * HD_ + h * D_;
    orow[lj] = f2bf(o0[r] * inv);
    orow[16 + lj] = f2bf(o1[r] * inv);
    orow[32 + lj] = f2bf(o2[r] * inv);
    orow[48 + lj] = f2bf(o3[r] * inv);
  }
}

// ---------------------------------------------------------------------------
// out = attn[16384,512](bf16) @ W^T (W bf16 row-major as B[k][o]=W[o][k]) + bias
// ---------------------------------------------------------------------------
__global__ __launch_bounds__(256) void gemm_kernel(const u16* __restrict__ A,
                                                   const u16* __restrict__ Wb,
                                                   const float* __restrict__ bias,
                                                   float* __restrict__ out) {
  const int lane = threadIdx.x & 63;
  const int wave = threadIdx.x >> 6;
  const int lg = lane >> 4, lj = lane & 15;
  const int rb = blockIdx.x >> 3;  // 256 row blocks
  const int cb = blockIdx.x & 7;   // 8 col blocks
  const int n0 = rb * 64 + (wave >> 1) * 32;
  const int o0 = cb * 64 + (wave & 1) * 32;

  f32x4 c00 = {0.f, 0.f, 0.f, 0.f}, c01 = c00, c10 = c00, c11 = c00;

  for (int kt = 0; kt < HD_; kt += 32) {
    bf16x8 a0 = *(const bf16x8*)(A + (size_t)(n0 + lj) * HD_ + kt + lg * 8);
    bf16x8 a1 = *(const bf16x8*)(A + (size_t)(n0 + 16 + lj) * HD_ + kt + lg * 8);
    bf16x8 b0 = *(const bf16x8*)(Wb + (size_t)(o0 + lj) * HD_ + kt + lg * 8);
    bf16x8 b1 = *(const bf16x8*)(Wb + (size_t)(o0 + 16 + lj) * HD_ + kt + lg * 8);
    c00 = MFMA(a0, b0, c00);
    c01 = MFMA(a0, b1, c01);
    c10 = MFMA(a1, b0, c10);
    c11 = MFMA(a1, b1, c11);
  }

#pragma unroll
  for (int r = 0; r < 4; ++r) {
    const int r0 = n0 + lg * 4 + r;
    const int r1 = r0 + 16;
    out[(size_t)r0 * HD_ + o0 + lj] = c00[r] + bias[o0 + lj];
    out[(size_t)r0 * HD_ + o0 + 16 + lj] = c01[r] + bias[o0 + 16 + lj];
    out[(size_t)r1 * HD_ + o0 + lj] = c10[r] + bias[o0 + lj];
    out[(size_t)r1 * HD_ + o0 + 16 + lj] = c11[r] + bias[o0 + 16 + lj];
  }
}

// ---------------------------------------------------------------------------
extern "C" void kernel_launch(void* const* d_in, const int* in_sizes, int n_in,
                              void* d_out, int out_size, void* d_ws, size_t ws_size,
                              hipStream_t stream) {
  const float* q = (const float*)d_in[0];
  const float* k = (const float*)d_in[1];
  const float* v = (const float*)d_in[2];
  const float* w = (const float*)d_in[3];
  const float* bias = (const float*)d_in[4];
  float* out = (float*)d_out;

  char* ws = (char*)d_ws;
  u16* vt = (u16*)ws;                        // 16,777,216 B : V^T bf16 [B,H,D,S]
  u16* kbb = (u16*)(ws + 16777216);          // 16,777,216 B : K bf16 [B,S,H,D]
  u16* attn = (u16*)(ws + 33554432);         // 16,777,216 B : attn bf16 [B*S, 512]
  u16* wb = (u16*)(ws + 50331648);           //    524,288 B : W bf16 [512,512]

  hipLaunchKernelGGL(vtrans_kernel, dim3(2048), dim3(256), 0, stream, v, vt);
  hipLaunchKernelGGL(cvt_kernel, dim3(8192), dim3(256), 0, stream, k, kbb, 2097152);
  hipLaunchKernelGGL(cvt_kernel, dim3(256), dim3(256), 0, stream, w, wb, 65536);
  // attention: B*H*(S/128) = 1024 blocks x 8 waves (16 queries each, shared K/V)
  hipLaunchKernelGGL(attn_kernel, dim3(1024), dim3(512), 0, stream, q, kbb, vt, attn);
  hipLaunchKernelGGL(gemm_kernel, dim3(2048), dim3(256), 0, stream, attn, wb, bias, out);
}

// Round 9
// 94.743 us; speedup vs baseline: 2.6072x; 1.4659x over previous
//
#include <hip/hip_runtime.h>

#define B_ 2
#define S_ 8192
#define H_ 8
#define D_ 64
#define HD_ 512
#define WIN_ 512

typedef __bf16 bf16x8 __attribute__((ext_vector_type(8)));
typedef float f32x4 __attribute__((ext_vector_type(4)));
typedef unsigned short u16;
typedef unsigned int u32;

__device__ __forceinline__ u16 f2bf(float f) {
  u32 u = __float_as_uint(f);
  u += 0x7FFFu + ((u >> 16) & 1u);
  return (u16)(u >> 16);
}

__device__ __forceinline__ bf16x8 cvt8s(const float* p, float s) {
  const float4 a = *(const float4*)p;
  const float4 b = *(const float4*)(p + 4);
  union { u16 s[8]; bf16x8 v; } r;
  r.s[0] = f2bf(a.x * s); r.s[1] = f2bf(a.y * s); r.s[2] = f2bf(a.z * s); r.s[3] = f2bf(a.w * s);
  r.s[4] = f2bf(b.x * s); r.s[5] = f2bf(b.y * s); r.s[6] = f2bf(b.z * s); r.s[7] = f2bf(b.w * s);
  return r.v;
}

#define MFMA(a, b, c) __builtin_amdgcn_mfma_f32_16x16x32_bf16(a, b, c, 0, 0, 0)

// ---------------------------------------------------------------------------
// V [B,S,H,D] fp32 -> Vt [B,H,D,S] bf16  (LDS-tiled transpose, 64x64 tiles)
// ---------------------------------------------------------------------------
__global__ __launch_bounds__(256) void vtrans_kernel(const float* __restrict__ v,
                                                     u16* __restrict__ vt) {
  const int t = threadIdx.x;
  const int s0 = (blockIdx.x & (S_ / 64 - 1)) * 64;
  const int bh = blockIdx.x >> 7;  // S_/64 = 128
  const int b = bh >> 3, h = bh & 7;
  __shared__ float tile[64][65];
#pragma unroll
  for (int it = 0; it < 16; ++it) {
    int idx = it * 256 + t;
    int r = idx >> 6, c = idx & 63;
    tile[r][c] = v[((size_t)(b * S_ + s0 + r) * H_ + h) * D_ + c];
  }
  __syncthreads();
#pragma unroll
  for (int it = 0; it < 16; ++it) {
    int idx = it * 256 + t;
    int dd = idx >> 6, c = idx & 63;
    vt[((size_t)(b * H_ + h) * D_ + dd) * S_ + s0 + c] = f2bf(tile[c][dd]);
  }
}

// ---------------------------------------------------------------------------
// generic fp32 -> bf16 conversion (vectorized x4)
// ---------------------------------------------------------------------------
__global__ __launch_bounds__(256) void cvt_kernel(const float* __restrict__ in,
                                                  u16* __restrict__ out, int n4) {
  int i = blockIdx.x * 256 + threadIdx.x;
  if (i < n4) {
    float4 f = ((const float4*)in)[i];
    ushort4 r;
    r.x = f2bf(f.x); r.y = f2bf(f.y); r.z = f2bf(f.z); r.w = f2bf(f.w);
    ((ushort4*)out)[i] = r;
  }
}

// ---------------------------------------------------------------------------
// Block-cooperative sliding-window flash attention (unchanged from R8).
// ---------------------------------------------------------------------------
__global__ __launch_bounds__(512) void attn_kernel(const float* __restrict__ q,
                                                   const u16* __restrict__ kb,
                                                   const u16* __restrict__ vt,
                                                   u16* __restrict__ attn) {
  const int tid = threadIdx.x;
  const int lane = tid & 63;
  const int wave = tid >> 6;
  const int lg = lane >> 4;   // 0..3
  const int lj = lane & 15;   // 0..15
  const int bid = (int)blockIdx.x;
  const int swz = (bid & 7) * 128 + (bid >> 3);
  const int qc = swz & 63;
  const int bh = swz >> 6;
  const int b = bh >> 3, h = bh & 7;
  const int q0blk = qc * 128;
  const int q0w = q0blk + wave * 16;

  __shared__ __align__(16) u16 klds0[32 * 64], klds1[32 * 64];
  __shared__ __align__(16) u16 vlds0[64 * 32], vlds1[64 * 32];
  __shared__ __align__(16) u16 plds[8][16][32];

  const float qscale = 0.125f * 1.4426950408889634f;
  bf16x8 aq0, aq1;
  {
    const float* qrow = q + ((size_t)(b * S_ + q0w + lj) * H_ + h) * D_;
    aq0 = cvt8s(qrow + lg * 8, qscale);
    aq1 = cvt8s(qrow + 32 + lg * 8, qscale);
  }

  f32x4 o0 = {0.f, 0.f, 0.f, 0.f}, o1 = o0, o2 = o0, o3 = o0;
  float lacc[4] = {0.f, 0.f, 0.f, 0.f};

  const int tbw = (q0w >= WIN_) ? ((q0w - (WIN_ - 1)) >> 5) : 0;
  const int tew = (q0w + 15) >> 5;
  const int tbu = (q0blk >= WIN_) ? ((q0blk - (WIN_ - 1)) >> 5) : 0;
  const int teu = (q0blk + 127) >> 5;
  const bool wmask = (q0w >= WIN_);

  const bool isK = (wave < 4);
  const u16* gbase;
  size_t gstep;
  u16 *l0, *l1;
  if (isK) {
    const int chunk = wave * 64 + lane;
    const int r = chunk >> 3, c = chunk & 7;
    gbase = kb + ((size_t)(b * S_ + r) * H_ + h) * D_ + c * 8;
    gstep = (size_t)32 * HD_;
    const int dst = r * 64 + ((c * 8) ^ ((r & 7) << 3));
    l0 = klds0 + dst; l1 = klds1 + dst;
  } else {
    const int chunk = (wave - 4) * 64 + lane;
    const int d = chunk >> 2, c = chunk & 3;
    gbase = vt + ((size_t)(b * H_ + h) * D_ + d) * S_ + c * 8;
    gstep = 32;
    const int dst = d * 32 + ((c * 8) ^ ((d & 3) << 3));
    l0 = vlds0 + dst; l1 = vlds1 + dst;
  }

  const int ko0 = lj * 64 + ((lg * 8) ^ ((lj & 7) << 3));
  const int ko1 = lj * 64 + (((32 + lg * 8)) ^ ((lj & 7) << 3));
  const int vo = lj * 32 + ((lg * 8) ^ ((lj & 3) << 3));

  {
    uint4 g0 = *(const uint4*)(gbase + gstep * tbu);
    *(uint4*)l0 = g0;
  }
  uint4 greg;
  if (tbu < teu) greg = *(const uint4*)(gbase + gstep * (tbu + 1));
  __syncthreads();

  int cur = 0;
  for (int t = tbu; t <= teu; ++t) {
    if (t >= tbw && t <= tew) {
      const u16* K = cur ? klds1 : klds0;
      const u16* V = cur ? vlds1 : vlds0;
      bf16x8 k00 = *(const bf16x8*)(K + ko0);
      bf16x8 k01 = *(const bf16x8*)(K + ko1);
      bf16x8 k10 = *(const bf16x8*)(K + ko0 + 1024);
      bf16x8 k11 = *(const bf16x8*)(K + ko1 + 1024);

      f32x4 sA = {0.f, 0.f, 0.f, 0.f}, sB = sA;
      sA = MFMA(aq0, k00, sA);
      sA = MFMA(aq1, k01, sA);
      sB = MFMA(aq0, k10, sB);
      sB = MFMA(aq1, k11, sB);

      const bool edge = (t == tew) || (wmask && t == tbw);
      float pa[4], pb[4];
#pragma unroll
      for (int r = 0; r < 4; ++r) {
        float ea = __builtin_amdgcn_exp2f(sA[r]);
        float eb = __builtin_amdgcn_exp2f(sB[r]);
        if (edge) {
          const int qpos = q0w + lg * 4 + r;
          const int kA = 32 * t + lj, kB = kA + 16;
          const bool okA = (kA <= qpos) && (kA > qpos - WIN_);
          const bool okB = (kB <= qpos) && (kB > qpos - WIN_);
          ea = okA ? ea : 0.f;
          eb = okB ? eb : 0.f;
        }
        pa[r] = ea; pb[r] = eb;
        lacc[r] += ea + eb;
      }

      u16* ps = &plds[wave][0][0];
#pragma unroll
      for (int r = 0; r < 4; ++r) {
        ps[(lg * 4 + r) * 32 + lj] = f2bf(pa[r]);
        ps[(lg * 4 + r) * 32 + 16 + lj] = f2bf(pb[r]);
      }
      bf16x8 ap = *(const bf16x8*)(ps + lj * 32 + lg * 8);

      bf16x8 v0 = *(const bf16x8*)(V + vo);
      bf16x8 v1 = *(const bf16x8*)(V + vo + 512);
      bf16x8 v2 = *(const bf16x8*)(V + vo + 1024);
      bf16x8 v3 = *(const bf16x8*)(V + vo + 1536);
      o0 = MFMA(ap, v0, o0);
      o1 = MFMA(ap, v1, o1);
      o2 = MFMA(ap, v2, o2);
      o3 = MFMA(ap, v3, o3);
    }

    if (t < teu) {
      u16* dst = cur ? l0 : l1;
      *(uint4*)dst = greg;
    }
    __syncthreads();
    if (t + 1 < teu) greg = *(const uint4*)(gbase + gstep * (t + 2));
    cur ^= 1;
  }

#pragma unroll
  for (int r = 0; r < 4; ++r) {
    float l = lacc[r];
    l += __shfl_xor(l, 1);
    l += __shfl_xor(l, 2);
    l += __shfl_xor(l, 4);
    l += __shfl_xor(l, 8);
    const float inv = 1.0f / l;
    const int row = q0w + lg * 4 + r;
    u16* orow = attn + (size_t)(b * S_ + row) * HD_ + h * D_;
    orow[lj] = f2bf(o0[r] * inv);
    orow[16 + lj] = f2bf(o1[r] * inv);
    orow[32 + lj] = f2bf(o2[r] * inv);
    orow[48 + lj] = f2bf(o3[r] * inv);
  }
}

// ---------------------------------------------------------------------------
// out = attn[16384,512](bf16) @ W^T + bias, fp32 out.
// Blocked: 512 threads, tile 128x256, BK=64. A staged in LDS (XOR-swizzled,
// double-buffered, reg prefetch). W (0.5MB) direct from L2. XCD swizzle:
// each XCD owns 16 contiguous row-blocks x both col-blocks (2MB of A in L2).
// ---------------------------------------------------------------------------
__global__ __launch_bounds__(512) void gemm_kernel(const u16* __restrict__ A,
                                                   const u16* __restrict__ Wb,
                                                   const float* __restrict__ bias,
                                                   float* __restrict__ out) {
  const int tid = threadIdx.x;
  const int lane = tid & 63;
  const int wave = tid >> 6;
  const int lg = lane >> 4, lj = lane & 15;
  // 256 blocks = 8 XCDs x 32 contiguous
  const int phys = (int)blockIdx.x;
  const int swz = (phys & 7) * 32 + (phys >> 3);
  const int rb = swz >> 1, cb = swz & 1;
  const int wr = wave >> 2, wc = wave & 3;    // wave grid 2x4
  const int row0 = rb * 128;
  const int col0 = cb * 256 + wc * 64;

  __shared__ __align__(16) u16 alds[2][128 * 64];  // 16KB each

  // staging: thread -> two 16B chunks (rows tid>>3 and 64+tid>>3, k-chunk tid&7)
  const int srow = tid >> 3;
  const int skc = tid & 7;
  const u16* ag0 = A + (size_t)(row0 + srow) * HD_ + skc * 8;
  const u16* ag1 = A + (size_t)(row0 + 64 + srow) * HD_ + skc * 8;
  const int dst0 = srow * 64 + ((skc * 8) ^ ((srow & 7) << 3));
  const int dst1 = (64 + srow) * 64 + ((skc * 8) ^ ((srow & 7) << 3));

  f32x4 acc[4][4];
#pragma unroll
  for (int fr = 0; fr < 4; ++fr)
#pragma unroll
    for (int fc = 0; fc < 4; ++fc) acc[fr][fc] = (f32x4){0.f, 0.f, 0.f, 0.f};

  // prologue: stage kt=0 into buf0
  *(uint4*)(&alds[0][dst0]) = *(const uint4*)ag0;
  *(uint4*)(&alds[0][dst1]) = *(const uint4*)ag1;
  __syncthreads();

  uint4 pre0, pre1;
  int cur = 0;
  for (int kt = 0; kt < HD_; kt += 64) {
    if (kt + 64 < HD_) {
      pre0 = *(const uint4*)(ag0 + kt + 64);
      pre1 = *(const uint4*)(ag1 + kt + 64);
    }
    const u16* Abuf = alds[cur];
#pragma unroll
    for (int ks = 0; ks < 2; ++ks) {
      bf16x8 fa[4], fb[4];
#pragma unroll
      for (int fr = 0; fr < 4; ++fr) {
        const int rr = wr * 64 + fr * 16 + lj;
        fa[fr] = *(const bf16x8*)(Abuf + rr * 64 + ((ks * 32 + lg * 8) ^ ((lj & 7) << 3)));
      }
#pragma unroll
      for (int fc = 0; fc < 4; ++fc)
        fb[fc] = *(const bf16x8*)(Wb + (size_t)(col0 + fc * 16 + lj) * HD_ + kt + ks * 32 + lg * 8);
#pragma unroll
      for (int fr = 0; fr < 4; ++fr)
#pragma unroll
        for (int fc = 0; fc < 4; ++fc)
          acc[fr][fc] = MFMA(fa[fr], fb[fc], acc[fr][fc]);
    }
    if (kt + 64 < HD_) {
      u16* db = alds[cur ^ 1];
      *(uint4*)(&db[dst0]) = pre0;
      *(uint4*)(&db[dst1]) = pre1;
    }
    __syncthreads();
    cur ^= 1;
  }

#pragma unroll
  for (int fc = 0; fc < 4; ++fc) {
    const float bv = bias[col0 + fc * 16 + lj];
#pragma unroll
    for (int fr = 0; fr < 4; ++fr) {
#pragma unroll
      for (int r = 0; r < 4; ++r) {
        const int row = row0 + wr * 64 + fr * 16 + lg * 4 + r;
        out[(size_t)row * HD_ + col0 + fc * 16 + lj] = acc[fr][fc][r] + bv;
      }
    }
  }
}

// ---------------------------------------------------------------------------
extern "C" void kernel_launch(void* const* d_in, const int* in_sizes, int n_in,
                              void* d_out, int out_size, void* d_ws, size_t ws_size,
                              hipStream_t stream) {
  const float* q = (const float*)d_in[0];
  const float* k = (const float*)d_in[1];
  const float* v = (const float*)d_in[2];
  const float* w = (const float*)d_in[3];
  const float* bias = (const float*)d_in[4];
  float* out = (float*)d_out;

  char* ws = (char*)d_ws;
  u16* vt = (u16*)ws;                        // 16,777,216 B : V^T bf16 [B,H,D,S]
  u16* kbb = (u16*)(ws + 16777216);          // 16,777,216 B : K bf16 [B,S,H,D]
  u16* attn = (u16*)(ws + 33554432);         // 16,777,216 B : attn bf16 [B*S, 512]
  u16* wb = (u16*)(ws + 50331648);           //    524,288 B : W bf16 [512,512]

  hipLaunchKernelGGL(vtrans_kernel, dim3(2048), dim3(256), 0, stream, v, vt);
  hipLaunchKernelGGL(cvt_kernel, dim3(8192), dim3(256), 0, stream, k, kbb, 2097152);
  hipLaunchKernelGGL(cvt_kernel, dim3(256), dim3(256), 0, stream, w, wb, 65536);
  // attention: B*H*(S/128) = 1024 blocks x 8 waves (16 queries each, shared K/V)
  hipLaunchKernelGGL(attn_kernel, dim3(1024), dim3(512), 0, stream, q, kbb, vt, attn);
  // out-projection: 128 row-blocks x 2 col-blocks = 256 blocks, 512 threads
  hipLaunchKernelGGL(gemm_kernel, dim3(256), dim3(512), 0, stream, attn, wb, bias, out);
}